// Round 4
// baseline (872.804 us; speedup 1.0000x reference)
//
#include <hip/hip_runtime.h>

#define B_ 16
#define N_ 16384
#define K_ 16

// ---- compact workspace layout (float offsets); total 56928 floats = 222 KB ----
enum : int {
  WS_LAT  = 0,      // 32 x 128 latent (f32, atomicMax-as-uint, relu>=0)
  WS_KPP  = 4096,   // 32 x 48 proposed keypoints
  WS_SEL  = 5632,   // 32 x 48 selected keypoints
  WS_PMIN = 7168,   // 16 x 3
  WS_PMAX = 7216,   // 16 x 3
  WS_CF   = 7264,   // 16 x 512 x 3 cage corners
  WS_W1F  = 31840,  // 64 x 3  bn-folded
  WS_B1F  = 32032,  // 64
  WS_W2F  = 32096,  // 128 x 64 bn-folded
  WS_B2F  = 40288,  // 128
  WS_W3F  = 40416,  // 128(c_in) x 128(out), transposed, scale3-folded
  WS_B3F  = 56800,  // 128
  WS_END  = 56928
};

enum : int { OUT_DEF=0, OUT_SRCKP=786432, OUT_TGTKP=787200 };

__device__ __forceinline__ float dist2rn(float px,float py,float pz,float sx,float sy,float sz){
  float dx=__fsub_rn(px,sx), dy=__fsub_rn(py,sy), dz=__fsub_rn(pz,sz);
  return __fadd_rn(__fadd_rn(__fmul_rn(dx,dx),__fmul_rn(dy,dy)),__fmul_rn(dz,dz));
}

// ---------------- prep: fold BN into encoder weights, w3 transposed -----------
struct EncW {
  const float *w1,*b1,*g1,*be1,*m1,*v1;
  const float *w2,*b2,*g2,*be2,*m2,*v2;
  const float *w3,*b3,*g3,*be3,*m3,*v3;
};

__device__ __forceinline__ float bn_scale(const float* g, const float* v, int ch){
  return g[ch] * (1.0f / sqrtf(v[ch] + 1e-5f));
}

__global__ void prep_kernel(EncW a, float* ws){
  const int stride = gridDim.x*blockDim.x;
  const int tid = blockIdx.x*blockDim.x + threadIdx.x;
  for (int i=tid;i<192;i+=stride){            // W1F
    int o=i/3;
    ws[WS_W1F+i] = a.w1[i] * bn_scale(a.g1,a.v1,o);
  }
  for (int i=tid;i<64;i+=stride){             // B1F = (b1-m1)*s1+be1
    float s = bn_scale(a.g1,a.v1,i);
    ws[WS_B1F+i] = (a.b1[i] - a.m1[i])*s + a.be1[i];
  }
  for (int i=tid;i<8192;i+=stride){           // W2F
    int o=i>>6;
    ws[WS_W2F+i] = a.w2[i] * bn_scale(a.g2,a.v2,o);
  }
  for (int i=tid;i<128;i+=stride){
    float s = bn_scale(a.g2,a.v2,i);
    ws[WS_B2F+i] = (a.b2[i] - a.m2[i])*s + a.be2[i];
  }
  for (int i=tid;i<16384;i+=stride){          // W3F[c][j] = w3[j][c]*s3[j]
    int c=i>>7, j=i&127;
    ws[WS_W3F+i] = a.w3[j*128+c] * bn_scale(a.g3,a.v3,j);
  }
  for (int i=tid;i<128;i+=stride){
    float s = bn_scale(a.g3,a.v3,i);
    ws[WS_B3F+i] = (a.b3[i] - a.m3[i])*s + a.be3[i];
  }
}

__global__ void zero_lat_kernel(float* ws){
  int i = blockIdx.x*blockDim.x + threadIdx.x;
  if (i < 4096) ws[WS_LAT + i] = 0.0f;
}

// ---------------- encoder: per-point MLP + max-reduce into lat ----------------
__global__ __launch_bounds__(256) void encode_kernel(const float* __restrict__ src,
                                                     const float* __restrict__ tgt,
                                                     const float* __restrict__ ws,
                                                     float* __restrict__ lat){
  const int cloud = blockIdx.y;
  const int n = blockIdx.x*256 + threadIdx.x;
  const float* base = (cloud < B_) ? (src + (size_t)cloud*N_*3)
                                   : (tgt + (size_t)(cloud-B_)*N_*3);
  __shared__ unsigned smax[128];
  if (threadIdx.x < 128) smax[threadIdx.x] = 0u;
  __syncthreads();

  const float x0 = base[n*3+0];
  const float x1 = base[n*3+1];
  const float x2 = base[n*3+2];

  const float* w1 = ws + WS_W1F;
  float h1[64];
  #pragma unroll
  for (int o=0;o<64;o++){
    float acc = fmaf(w1[o*3+2], x2, fmaf(w1[o*3+1], x1, w1[o*3]*x0)) + ws[WS_B1F+o];
    h1[o] = fmaxf(acc, 0.0f);
  }

  float acc3[128];
  #pragma unroll
  for (int j=0;j<128;j++) acc3[j]=0.0f;

  const float* w2  = ws + WS_W2F;
  const float* w3f = ws + WS_W3F;
  for (int o=0;o<128;o++){
    const float* w = w2 + o*64;
    float a0=0.f,a1=0.f,a2=0.f,a3=0.f;
    #pragma unroll
    for (int c=0;c<64;c+=4){
      a0 = fmaf(h1[c  ], w[c  ], a0);
      a1 = fmaf(h1[c+1], w[c+1], a1);
      a2 = fmaf(h1[c+2], w[c+2], a2);
      a3 = fmaf(h1[c+3], w[c+3], a3);
    }
    float h2v = fmaxf((a0+a1)+(a2+a3) + ws[WS_B2F+o], 0.0f);
    const float* w3r = w3f + o*128;
    #pragma unroll
    for (int j=0;j<128;j++) acc3[j] = fmaf(h2v, w3r[j], acc3[j]);
  }

  const int lane = threadIdx.x & 63;
  #pragma unroll
  for (int j=0;j<128;j++){
    float x = fmaxf(acc3[j] + ws[WS_B3F+j], 0.0f);   // relu>=0 -> uint order ok
    #pragma unroll
    for (int off=32; off>0; off>>=1) x = fmaxf(x, __shfl_down(x, off, 64));
    if (lane==0) atomicMax(&smax[j], __float_as_uint(x));
  }
  __syncthreads();
  if (threadIdx.x < 128)
    atomicMax((unsigned*)(lat + cloud*128 + threadIdx.x), smax[threadIdx.x]);
}

// ---------------- keypoint MLP: lat(128) -> 128 relu -> 48 --------------------
__global__ void kp_mlp_kernel(const float* __restrict__ ws,
                              const float* __restrict__ kw1, const float* __restrict__ kb1,
                              const float* __restrict__ kw2, const float* __restrict__ kb2,
                              float* __restrict__ wsm){
  const int cloud = blockIdx.x; const int t = threadIdx.x;
  __shared__ float h[128];
  const float* lat = ws + WS_LAT + cloud*128;
  if (t < 128){
    float acc = kb1[t];
    const float* w = kw1 + t*128;
    for (int c=0;c<128;c++) acc = fmaf(lat[c], w[c], acc);
    h[t] = fmaxf(acc, 0.0f);
  }
  __syncthreads();
  if (t < 48){
    float acc = kb2[t];
    const float* w = kw2 + t*128;
    for (int c=0;c<128;c++) acc = fmaf(h[c], w[c], acc);
    wsm[WS_KPP + cloud*48 + t] = acc;
  }
}

// ---------------- FPS (one block per cloud) -----------------------------------
__device__ int block_argmax(float v, int i, float* rv, int* ri, int t){
  __syncthreads();
  rv[t]=v; ri[t]=i;
  __syncthreads();
  for (int s=128; s>0; s>>=1){
    if (t < s){
      float v2 = rv[t+s]; int i2 = ri[t+s];
      if (v2 > rv[t] || (v2 == rv[t] && i2 < ri[t])){ rv[t]=v2; ri[t]=i2; }
    }
    __syncthreads();
  }
  return ri[0];   // first-index-on-tie == numpy argmax
}

__global__ __launch_bounds__(256) void fps_kernel(const float* __restrict__ src,
                                                  const float* __restrict__ tgt,
                                                  float* ws, float* out){
  const int cloud = blockIdx.x; const int t = threadIdx.x;
  const float* base = (cloud < B_) ? (src + (size_t)cloud*N_*3)
                                   : (tgt + (size_t)(cloud-B_)*N_*3);
  __shared__ float rv[256]; __shared__ int ri[256]; __shared__ float sel[3];
  const float* kp = ws + WS_KPP + cloud*48;

  // phase A: d0 = min over proposed kps, argmax
  float bv = -1.0f; int bi = 0;
  for (int k=0;k<64;k++){
    int n = t + k*256;
    float px=base[n*3], py=base[n*3+1], pz=base[n*3+2];
    float dmin = 3.4028235e38f;
    #pragma unroll
    for (int j=0;j<K_;j++)
      dmin = fminf(dmin, dist2rn(px,py,pz, kp[j*3],kp[j*3+1],kp[j*3+2]));
    if (dmin > bv){ bv = dmin; bi = n; }
  }
  int idx = block_argmax(bv, bi, rv, ri, t);
  if (t==0){ sel[0]=base[idx*3]; sel[1]=base[idx*3+1]; sel[2]=base[idx*3+2]; }
  __syncthreads();
  float s0=sel[0], s1=sel[1], s2=sel[2];
  if (t==0){
    float* sw = ws + WS_SEL + cloud*48;
    sw[0]=s0; sw[1]=s1; sw[2]=s2;
    size_t o = (cloud<B_) ? (size_t)(OUT_SRCKP + cloud*48) : (size_t)(OUT_TGTKP + (cloud-B_)*48);
    out[o]=s0; out[o+1]=s1; out[o+2]=s2;
  }

  // phase B: mind = dist to sel0 (fresh, per reference), track argmax
  float mind[64];
  bv = -1.0f; bi = 0;
  #pragma unroll
  for (int k=0;k<64;k++){
    int n = t + k*256;
    float px=base[n*3], py=base[n*3+1], pz=base[n*3+2];
    float d = dist2rn(px,py,pz, s0,s1,s2);
    mind[k]=d;
    if (d > bv){ bv=d; bi=n; }
  }

  for (int it=1; it<K_; it++){
    idx = block_argmax(bv, bi, rv, ri, t);
    if (t==0){ sel[0]=base[idx*3]; sel[1]=base[idx*3+1]; sel[2]=base[idx*3+2]; }
    __syncthreads();
    s0=sel[0]; s1=sel[1]; s2=sel[2];
    if (t==0){
      float* sw = ws + WS_SEL + cloud*48 + it*3;
      sw[0]=s0; sw[1]=s1; sw[2]=s2;
      size_t o = (cloud<B_) ? (size_t)(OUT_SRCKP + cloud*48 + it*3) : (size_t)(OUT_TGTKP + (cloud-B_)*48 + it*3);
      out[o]=s0; out[o+1]=s1; out[o+2]=s2;
    }
    if (it < K_-1){
      bv=-1.0f; bi=0;
      #pragma unroll
      for (int k=0;k<64;k++){
        int n = t + k*256;
        float px=base[n*3], py=base[n*3+1], pz=base[n*3+2];
        float d = dist2rn(px,py,pz, s0,s1,s2);
        float m = fminf(mind[k], d);
        mind[k]=m;
        if (m > bv){ bv=m; bi=n; }
      }
    }
  }
}

// ---------------- per-batch source min/max ------------------------------------
__global__ void pminmax_kernel(const float* __restrict__ src, float* ws){
  __shared__ float red[256];
  const int b=blockIdx.x, t=threadIdx.x;
  const float* base = src + (size_t)b*N_*3;
  float mn[3]={3.4e38f,3.4e38f,3.4e38f}, mx[3]={-3.4e38f,-3.4e38f,-3.4e38f};
  for (int n=t;n<N_;n+=256){
    #pragma unroll
    for (int c=0;c<3;c++){
      float v=base[n*3+c];
      mn[c]=fminf(mn[c],v); mx[c]=fmaxf(mx[c],v);
    }
  }
  for (int c=0;c<3;c++){
    red[t]=mn[c]; __syncthreads();
    for (int s=128;s>0;s>>=1){ if(t<s) red[t]=fminf(red[t],red[t+s]); __syncthreads(); }
    if (t==0) ws[WS_PMIN+b*3+c]=red[0];
    __syncthreads();
    red[t]=mx[c]; __syncthreads();
    for (int s=128;s>0;s>>=1){ if(t<s) red[t]=fmaxf(red[t],red[t+s]); __syncthreads(); }
    if (t==0) ws[WS_PMAX+b*3+c]=red[0];
    __syncthreads();
  }
}

// ---------------- cage MLP + corner grid --------------------------------------
__global__ void cage_mlp_kernel(const float* __restrict__ ws,
                                const float* __restrict__ cw1, const float* __restrict__ cb1,
                                const float* __restrict__ cw2, const float* __restrict__ cb2,
                                float* __restrict__ wsm){
  const int b = blockIdx.x; const int t = threadIdx.x;
  __shared__ float diff[48]; __shared__ float h[128];
  if (t<48) diff[t] = __fsub_rn(ws[WS_SEL + (B_+b)*48 + t], ws[WS_SEL + b*48 + t]);
  __syncthreads();
  if (t<128){
    const float* w = cw1 + t*48;
    float acc = cb1[t];
    for (int j=0;j<48;j++) acc = fmaf(diff[j], w[j], acc);
    h[t] = fmaxf(acc, 0.0f);
  }
  __syncthreads();
  for (int o=t;o<1536;o+=256){
    const float* w = cw2 + o*128;
    float acc = cb2[o];
    for (int c=0;c<128;c++) acc = fmaf(h[c], w[c], acc);
    int flat = o/3, coord = o - flat*3;
    int u = flat>>6, v=(flat>>3)&7, z=flat&7;
    int g = (coord==0)?u:((coord==1)?v:z);
    float gv = (g==7)?1.0f:(float)g*(1.0f/7.0f);
    wsm[WS_CF + b*1536 + o] = gv + acc;
  }
}

// ---------------- trilinear cage deform ---------------------------------------
__global__ __launch_bounds__(256) void deform_kernel(const float* __restrict__ src,
                                                     const float* __restrict__ ws,
                                                     float* __restrict__ out){
  const int b = blockIdx.y;
  const int n = blockIdx.x*256 + threadIdx.x;
  __shared__ float cf[1536];
  for (int i=threadIdx.x;i<1536;i+=256) cf[i] = ws[WS_CF + b*1536 + i];
  __syncthreads();

  const float* p = src + ((size_t)b*N_ + n)*3;
  float pt[3]; int id[3]; float w[3];
  #pragma unroll
  for (int c=0;c<3;c++){
    float pv = p[c];
    float mn = ws[WS_PMIN+b*3+c], mxv = ws[WS_PMAX+b*3+c];
    float denom = __fadd_rn(__fsub_rn(mxv, mn), 1e-6f);
    float tc = __fmul_rn(__fdiv_rn(__fsub_rn(pv, mn), denom), 7.0f);
    int ic = (int)tc; ic = min(max(ic,0),6);
    pt[c]=pv; id[c]=ic; w[c]=__fsub_rn(tc, (float)ic);
  }
  const int flat = (id[0]<<6) + (id[1]<<3) + id[2];
  const float* c000 = cf + flat*3;
  const float wx=w[0], wy=w[1], wz=w[2];
  const float ux=__fsub_rn(1.0f,wx), uy=__fsub_rn(1.0f,wy), uz=__fsub_rn(1.0f,wz);
  const float w000=__fmul_rn(__fmul_rn(ux,uy),uz);
  const float w100=__fmul_rn(__fmul_rn(wx,uy),uz);
  const float w010=__fmul_rn(__fmul_rn(ux,wy),uz);
  const float w110=__fmul_rn(__fmul_rn(wx,wy),uz);
  const float w001=__fmul_rn(__fmul_rn(ux,uy),wz);
  const float w101=__fmul_rn(__fmul_rn(wx,uy),wz);
  const float w011=__fmul_rn(__fmul_rn(ux,wy),wz);
  const float w111=__fmul_rn(__fmul_rn(wx,wy),wz);
  #pragma unroll
  for (int c=0;c<3;c++){
    float d = __fmul_rn(w000, c000[c]);
    d = __fadd_rn(d, __fmul_rn(w100, c000[192+c]));  // (+1,0,0) -> +64*3
    d = __fadd_rn(d, __fmul_rn(w010, c000[24+c]));   // (0,+1,0) -> +8*3
    d = __fadd_rn(d, __fmul_rn(w110, c000[216+c]));
    d = __fadd_rn(d, __fmul_rn(w001, c000[3+c]));    // (0,0,+1) -> +3
    d = __fadd_rn(d, __fmul_rn(w101, c000[195+c]));
    d = __fadd_rn(d, __fmul_rn(w011, c000[27+c]));
    d = __fadd_rn(d, __fmul_rn(w111, c000[219+c]));
    out[((size_t)b*N_+n)*3 + c] = __fadd_rn(pt[c], d);
  }
}

// ---------------- launch ------------------------------------------------------
extern "C" void kernel_launch(void* const* d_in, const int* in_sizes, int n_in,
                              void* d_out, int out_size, void* d_ws, size_t ws_size,
                              hipStream_t stream){
  const float* src = (const float*)d_in[0];
  const float* tgt = (const float*)d_in[1];
  float* ws = (float*)d_ws;
  float* out = (float*)d_out;

  EncW ew;
  ew.w1 =(const float*)d_in[2];  ew.b1 =(const float*)d_in[3];
  ew.g1 =(const float*)d_in[4];  ew.be1=(const float*)d_in[5];
  ew.m1 =(const float*)d_in[6];  ew.v1 =(const float*)d_in[7];
  ew.w2 =(const float*)d_in[8];  ew.b2 =(const float*)d_in[9];
  ew.g2 =(const float*)d_in[10]; ew.be2=(const float*)d_in[11];
  ew.m2 =(const float*)d_in[12]; ew.v2 =(const float*)d_in[13];
  ew.w3 =(const float*)d_in[14]; ew.b3 =(const float*)d_in[15];
  ew.g3 =(const float*)d_in[16]; ew.be3=(const float*)d_in[17];
  ew.m3 =(const float*)d_in[18]; ew.v3 =(const float*)d_in[19];

  prep_kernel<<<128, 256, 0, stream>>>(ew, ws);
  zero_lat_kernel<<<16, 256, 0, stream>>>(ws);
  encode_kernel<<<dim3(64,32), 256, 0, stream>>>(src, tgt, ws, ws + WS_LAT);
  kp_mlp_kernel<<<32, 128, 0, stream>>>(ws,
      (const float*)d_in[20], (const float*)d_in[21],
      (const float*)d_in[22], (const float*)d_in[23], ws);
  fps_kernel<<<32, 256, 0, stream>>>(src, tgt, ws, out);
  pminmax_kernel<<<16, 256, 0, stream>>>(src, ws);
  cage_mlp_kernel<<<16, 256, 0, stream>>>(ws,
      (const float*)d_in[24], (const float*)d_in[25],
      (const float*)d_in[26], (const float*)d_in[27], ws);
  deform_kernel<<<dim3(64,16), 256, 0, stream>>>(src, ws, out);
}

// Round 5
// 863.065 us; speedup vs baseline: 1.0113x; 1.0113x over previous
//
#include <hip/hip_runtime.h>

#define B_ 16
#define N_ 16384
#define K_ 16

// ---- compact workspace layout (float offsets); total 56928 floats = 222 KB ----
enum : int {
  WS_LAT  = 0,      // 32 x 128 latent (f32, atomicMax-as-uint, relu>=0)
  WS_KPP  = 4096,   // 32 x 48 proposed keypoints
  WS_SEL  = 5632,   // 32 x 48 selected keypoints
  WS_PMIN = 7168,   // 16 x 3
  WS_PMAX = 7216,   // 16 x 3
  WS_CF   = 7264,   // 16 x 512 x 3 cage corners
  WS_W1F  = 31840,  // 64 x 3  bn-folded
  WS_B1F  = 32032,  // 64
  WS_W2F  = 32096,  // 128 x 64 bn-folded
  WS_B2F  = 40288,  // 128
  WS_W3F  = 40416,  // 128(c_in) x 128(out), transposed, scale3-folded
  WS_B3F  = 56800,  // 128
  WS_END  = 56928
};

enum : int { OUT_DEF=0, OUT_SRCKP=786432, OUT_TGTKP=787200 };

__device__ __forceinline__ float dist2rn(float px,float py,float pz,float sx,float sy,float sz){
  float dx=__fsub_rn(px,sx), dy=__fsub_rn(py,sy), dz=__fsub_rn(pz,sz);
  return __fadd_rn(__fadd_rn(__fmul_rn(dx,dx),__fmul_rn(dy,dy)),__fmul_rn(dz,dz));
}

// ---------------- prep: fold BN into encoder weights, w3 transposed -----------
struct EncW {
  const float *w1,*b1,*g1,*be1,*m1,*v1;
  const float *w2,*b2,*g2,*be2,*m2,*v2;
  const float *w3,*b3,*g3,*be3,*m3,*v3;
};

__device__ __forceinline__ float bn_scale(const float* g, const float* v, int ch){
  return g[ch] * (1.0f / sqrtf(v[ch] + 1e-5f));
}

__global__ void prep_kernel(EncW a, float* ws){
  const int stride = gridDim.x*blockDim.x;
  const int tid = blockIdx.x*blockDim.x + threadIdx.x;
  for (int i=tid;i<4096;i+=stride)            // zero latent (atomicMax target)
    ws[WS_LAT+i] = 0.0f;
  for (int i=tid;i<192;i+=stride){            // W1F
    int o=i/3;
    ws[WS_W1F+i] = a.w1[i] * bn_scale(a.g1,a.v1,o);
  }
  for (int i=tid;i<64;i+=stride){             // B1F = (b1-m1)*s1+be1
    float s = bn_scale(a.g1,a.v1,i);
    ws[WS_B1F+i] = (a.b1[i] - a.m1[i])*s + a.be1[i];
  }
  for (int i=tid;i<8192;i+=stride){           // W2F
    int o=i>>6;
    ws[WS_W2F+i] = a.w2[i] * bn_scale(a.g2,a.v2,o);
  }
  for (int i=tid;i<128;i+=stride){
    float s = bn_scale(a.g2,a.v2,i);
    ws[WS_B2F+i] = (a.b2[i] - a.m2[i])*s + a.be2[i];
  }
  for (int i=tid;i<16384;i+=stride){          // W3F[c][j] = w3[j][c]*s3[j]
    int c=i>>7, j=i&127;
    ws[WS_W3F+i] = a.w3[j*128+c] * bn_scale(a.g3,a.v3,j);
  }
  for (int i=tid;i<128;i+=stride){
    float s = bn_scale(a.g3,a.v3,i);
    ws[WS_B3F+i] = (a.b3[i] - a.m3[i])*s + a.be3[i];
  }
}

// ---------------- encoder: per-point MLP + max-reduce into lat ----------------
// __launch_bounds__(256, 1): allow ~512 VGPR/wave so h1[64]+acc3[128] stay in
// architectural VGPRs. Default heuristic capped at 100 VGPR and shuttled acc3
// through AGPRs (v_accvgpr_read/write per FMA) -> ~2.2x VALU inflation (R4 PMC:
// VALUBusy 41%, 584us vs 165us FMA floor).
__global__ __launch_bounds__(256, 1) void encode_kernel(const float* __restrict__ src,
                                                        const float* __restrict__ tgt,
                                                        const float* __restrict__ ws,
                                                        float* __restrict__ lat){
  const int cloud = blockIdx.y;
  const int n = blockIdx.x*256 + threadIdx.x;
  const float* base = (cloud < B_) ? (src + (size_t)cloud*N_*3)
                                   : (tgt + (size_t)(cloud-B_)*N_*3);
  __shared__ unsigned smax[128];
  if (threadIdx.x < 128) smax[threadIdx.x] = 0u;
  __syncthreads();

  const float x0 = base[n*3+0];
  const float x1 = base[n*3+1];
  const float x2 = base[n*3+2];

  const float* w1 = ws + WS_W1F;
  float h1[64];
  #pragma unroll
  for (int o=0;o<64;o++){
    float acc = fmaf(w1[o*3+2], x2, fmaf(w1[o*3+1], x1, w1[o*3]*x0)) + ws[WS_B1F+o];
    h1[o] = fmaxf(acc, 0.0f);
  }

  float acc3[128];
  #pragma unroll
  for (int j=0;j<128;j++) acc3[j]=0.0f;

  const float* w2  = ws + WS_W2F;
  const float* w3f = ws + WS_W3F;
  for (int o=0;o<128;o++){
    const float* w = w2 + o*64;
    float a0=0.f,a1=0.f,a2=0.f,a3=0.f;
    #pragma unroll
    for (int c=0;c<64;c+=4){
      a0 = fmaf(h1[c  ], w[c  ], a0);
      a1 = fmaf(h1[c+1], w[c+1], a1);
      a2 = fmaf(h1[c+2], w[c+2], a2);
      a3 = fmaf(h1[c+3], w[c+3], a3);
    }
    float h2v = fmaxf((a0+a1)+(a2+a3) + ws[WS_B2F+o], 0.0f);
    const float* w3r = w3f + o*128;
    #pragma unroll
    for (int j=0;j<128;j++) acc3[j] = fmaf(h2v, w3r[j], acc3[j]);
  }

  const int lane = threadIdx.x & 63;
  #pragma unroll
  for (int j=0;j<128;j++){
    float x = fmaxf(acc3[j] + ws[WS_B3F+j], 0.0f);   // relu>=0 -> uint order ok
    #pragma unroll
    for (int off=32; off>0; off>>=1) x = fmaxf(x, __shfl_down(x, off, 64));
    if (lane==0) atomicMax(&smax[j], __float_as_uint(x));
  }
  __syncthreads();
  if (threadIdx.x < 128)
    atomicMax((unsigned*)(lat + cloud*128 + threadIdx.x), smax[threadIdx.x]);
}

// ---------------- keypoint MLP: lat(128) -> 128 relu -> 48 --------------------
__global__ void kp_mlp_kernel(const float* __restrict__ ws,
                              const float* __restrict__ kw1, const float* __restrict__ kb1,
                              const float* __restrict__ kw2, const float* __restrict__ kb2,
                              float* __restrict__ wsm){
  const int cloud = blockIdx.x; const int t = threadIdx.x;
  __shared__ float h[128];
  const float* lat = ws + WS_LAT + cloud*128;
  if (t < 128){
    float acc = kb1[t];
    const float* w = kw1 + t*128;
    for (int c=0;c<128;c++) acc = fmaf(lat[c], w[c], acc);
    h[t] = fmaxf(acc, 0.0f);
  }
  __syncthreads();
  if (t < 48){
    float acc = kb2[t];
    const float* w = kw2 + t*128;
    for (int c=0;c<128;c++) acc = fmaf(h[c], w[c], acc);
    wsm[WS_KPP + cloud*48 + t] = acc;
  }
}

// ---------------- FPS (one block per cloud) -----------------------------------
__device__ int block_argmax(float v, int i, float* rv, int* ri, int t){
  __syncthreads();
  rv[t]=v; ri[t]=i;
  __syncthreads();
  for (int s=128; s>0; s>>=1){
    if (t < s){
      float v2 = rv[t+s]; int i2 = ri[t+s];
      if (v2 > rv[t] || (v2 == rv[t] && i2 < ri[t])){ rv[t]=v2; ri[t]=i2; }
    }
    __syncthreads();
  }
  return ri[0];   // first-index-on-tie == numpy argmax
}

__global__ __launch_bounds__(256) void fps_kernel(const float* __restrict__ src,
                                                  const float* __restrict__ tgt,
                                                  float* ws, float* out){
  const int cloud = blockIdx.x; const int t = threadIdx.x;
  const float* base = (cloud < B_) ? (src + (size_t)cloud*N_*3)
                                   : (tgt + (size_t)(cloud-B_)*N_*3);
  __shared__ float rv[256]; __shared__ int ri[256]; __shared__ float sel[3];
  const float* kp = ws + WS_KPP + cloud*48;

  // phase A: d0 = min over proposed kps, argmax
  float bv = -1.0f; int bi = 0;
  for (int k=0;k<64;k++){
    int n = t + k*256;
    float px=base[n*3], py=base[n*3+1], pz=base[n*3+2];
    float dmin = 3.4028235e38f;
    #pragma unroll
    for (int j=0;j<K_;j++)
      dmin = fminf(dmin, dist2rn(px,py,pz, kp[j*3],kp[j*3+1],kp[j*3+2]));
    if (dmin > bv){ bv = dmin; bi = n; }
  }
  int idx = block_argmax(bv, bi, rv, ri, t);
  if (t==0){ sel[0]=base[idx*3]; sel[1]=base[idx*3+1]; sel[2]=base[idx*3+2]; }
  __syncthreads();
  float s0=sel[0], s1=sel[1], s2=sel[2];
  if (t==0){
    float* sw = ws + WS_SEL + cloud*48;
    sw[0]=s0; sw[1]=s1; sw[2]=s2;
    size_t o = (cloud<B_) ? (size_t)(OUT_SRCKP + cloud*48) : (size_t)(OUT_TGTKP + (cloud-B_)*48);
    out[o]=s0; out[o+1]=s1; out[o+2]=s2;
  }

  // phase B: mind = dist to sel0 (fresh, per reference), track argmax
  float mind[64];
  bv = -1.0f; bi = 0;
  #pragma unroll
  for (int k=0;k<64;k++){
    int n = t + k*256;
    float px=base[n*3], py=base[n*3+1], pz=base[n*3+2];
    float d = dist2rn(px,py,pz, s0,s1,s2);
    mind[k]=d;
    if (d > bv){ bv=d; bi=n; }
  }

  for (int it=1; it<K_; it++){
    idx = block_argmax(bv, bi, rv, ri, t);
    if (t==0){ sel[0]=base[idx*3]; sel[1]=base[idx*3+1]; sel[2]=base[idx*3+2]; }
    __syncthreads();
    s0=sel[0]; s1=sel[1]; s2=sel[2];
    if (t==0){
      float* sw = ws + WS_SEL + cloud*48 + it*3;
      sw[0]=s0; sw[1]=s1; sw[2]=s2;
      size_t o = (cloud<B_) ? (size_t)(OUT_SRCKP + cloud*48 + it*3) : (size_t)(OUT_TGTKP + (cloud-B_)*48 + it*3);
      out[o]=s0; out[o+1]=s1; out[o+2]=s2;
    }
    if (it < K_-1){
      bv=-1.0f; bi=0;
      #pragma unroll
      for (int k=0;k<64;k++){
        int n = t + k*256;
        float px=base[n*3], py=base[n*3+1], pz=base[n*3+2];
        float d = dist2rn(px,py,pz, s0,s1,s2);
        float m = fminf(mind[k], d);
        mind[k]=m;
        if (m > bv){ bv=m; bi=n; }
      }
    }
  }
}

// ---------------- per-batch source min/max ------------------------------------
__global__ void pminmax_kernel(const float* __restrict__ src, float* ws){
  __shared__ float red[256];
  const int b=blockIdx.x, t=threadIdx.x;
  const float* base = src + (size_t)b*N_*3;
  float mn[3]={3.4e38f,3.4e38f,3.4e38f}, mx[3]={-3.4e38f,-3.4e38f,-3.4e38f};
  for (int n=t;n<N_;n+=256){
    #pragma unroll
    for (int c=0;c<3;c++){
      float v=base[n*3+c];
      mn[c]=fminf(mn[c],v); mx[c]=fmaxf(mx[c],v);
    }
  }
  for (int c=0;c<3;c++){
    red[t]=mn[c]; __syncthreads();
    for (int s=128;s>0;s>>=1){ if(t<s) red[t]=fminf(red[t],red[t+s]); __syncthreads(); }
    if (t==0) ws[WS_PMIN+b*3+c]=red[0];
    __syncthreads();
    red[t]=mx[c]; __syncthreads();
    for (int s=128;s>0;s>>=1){ if(t<s) red[t]=fmaxf(red[t],red[t+s]); __syncthreads(); }
    if (t==0) ws[WS_PMAX+b*3+c]=red[0];
    __syncthreads();
  }
}

// ---------------- cage MLP + corner grid --------------------------------------
__global__ void cage_mlp_kernel(const float* __restrict__ ws,
                                const float* __restrict__ cw1, const float* __restrict__ cb1,
                                const float* __restrict__ cw2, const float* __restrict__ cb2,
                                float* __restrict__ wsm){
  const int b = blockIdx.x; const int t = threadIdx.x;
  __shared__ float diff[48]; __shared__ float h[128];
  if (t<48) diff[t] = __fsub_rn(ws[WS_SEL + (B_+b)*48 + t], ws[WS_SEL + b*48 + t]);
  __syncthreads();
  if (t<128){
    const float* w = cw1 + t*48;
    float acc = cb1[t];
    for (int j=0;j<48;j++) acc = fmaf(diff[j], w[j], acc);
    h[t] = fmaxf(acc, 0.0f);
  }
  __syncthreads();
  for (int o=t;o<1536;o+=256){
    const float* w = cw2 + o*128;
    float acc = cb2[o];
    for (int c=0;c<128;c++) acc = fmaf(h[c], w[c], acc);
    int flat = o/3, coord = o - flat*3;
    int u = flat>>6, v=(flat>>3)&7, z=flat&7;
    int g = (coord==0)?u:((coord==1)?v:z);
    float gv = (g==7)?1.0f:(float)g*(1.0f/7.0f);
    wsm[WS_CF + b*1536 + o] = gv + acc;
  }
}

// ---------------- trilinear cage deform ---------------------------------------
__global__ __launch_bounds__(256) void deform_kernel(const float* __restrict__ src,
                                                     const float* __restrict__ ws,
                                                     float* __restrict__ out){
  const int b = blockIdx.y;
  const int n = blockIdx.x*256 + threadIdx.x;
  __shared__ float cf[1536];
  for (int i=threadIdx.x;i<1536;i+=256) cf[i] = ws[WS_CF + b*1536 + i];
  __syncthreads();

  const float* p = src + ((size_t)b*N_ + n)*3;
  float pt[3]; int id[3]; float w[3];
  #pragma unroll
  for (int c=0;c<3;c++){
    float pv = p[c];
    float mn = ws[WS_PMIN+b*3+c], mxv = ws[WS_PMAX+b*3+c];
    float denom = __fadd_rn(__fsub_rn(mxv, mn), 1e-6f);
    float tc = __fmul_rn(__fdiv_rn(__fsub_rn(pv, mn), denom), 7.0f);
    int ic = (int)tc; ic = min(max(ic,0),6);
    pt[c]=pv; id[c]=ic; w[c]=__fsub_rn(tc, (float)ic);
  }
  const int flat = (id[0]<<6) + (id[1]<<3) + id[2];
  const float* c000 = cf + flat*3;
  const float wx=w[0], wy=w[1], wz=w[2];
  const float ux=__fsub_rn(1.0f,wx), uy=__fsub_rn(1.0f,wy), uz=__fsub_rn(1.0f,wz);
  const float w000=__fmul_rn(__fmul_rn(ux,uy),uz);
  const float w100=__fmul_rn(__fmul_rn(wx,uy),uz);
  const float w010=__fmul_rn(__fmul_rn(ux,wy),uz);
  const float w110=__fmul_rn(__fmul_rn(wx,wy),uz);
  const float w001=__fmul_rn(__fmul_rn(ux,uy),wz);
  const float w101=__fmul_rn(__fmul_rn(wx,uy),wz);
  const float w011=__fmul_rn(__fmul_rn(ux,wy),wz);
  const float w111=__fmul_rn(__fmul_rn(wx,wy),wz);
  #pragma unroll
  for (int c=0;c<3;c++){
    float d = __fmul_rn(w000, c000[c]);
    d = __fadd_rn(d, __fmul_rn(w100, c000[192+c]));  // (+1,0,0) -> +64*3
    d = __fadd_rn(d, __fmul_rn(w010, c000[24+c]));   // (0,+1,0) -> +8*3
    d = __fadd_rn(d, __fmul_rn(w110, c000[216+c]));
    d = __fadd_rn(d, __fmul_rn(w001, c000[3+c]));    // (0,0,+1) -> +3
    d = __fadd_rn(d, __fmul_rn(w101, c000[195+c]));
    d = __fadd_rn(d, __fmul_rn(w011, c000[27+c]));
    d = __fadd_rn(d, __fmul_rn(w111, c000[219+c]));
    out[((size_t)b*N_+n)*3 + c] = __fadd_rn(pt[c], d);
  }
}

// ---------------- launch ------------------------------------------------------
extern "C" void kernel_launch(void* const* d_in, const int* in_sizes, int n_in,
                              void* d_out, int out_size, void* d_ws, size_t ws_size,
                              hipStream_t stream){
  const float* src = (const float*)d_in[0];
  const float* tgt = (const float*)d_in[1];
  float* ws = (float*)d_ws;
  float* out = (float*)d_out;

  EncW ew;
  ew.w1 =(const float*)d_in[2];  ew.b1 =(const float*)d_in[3];
  ew.g1 =(const float*)d_in[4];  ew.be1=(const float*)d_in[5];
  ew.m1 =(const float*)d_in[6];  ew.v1 =(const float*)d_in[7];
  ew.w2 =(const float*)d_in[8];  ew.b2 =(const float*)d_in[9];
  ew.g2 =(const float*)d_in[10]; ew.be2=(const float*)d_in[11];
  ew.m2 =(const float*)d_in[12]; ew.v2 =(const float*)d_in[13];
  ew.w3 =(const float*)d_in[14]; ew.b3 =(const float*)d_in[15];
  ew.g3 =(const float*)d_in[16]; ew.be3=(const float*)d_in[17];
  ew.m3 =(const float*)d_in[18]; ew.v3 =(const float*)d_in[19];

  prep_kernel<<<128, 256, 0, stream>>>(ew, ws);
  encode_kernel<<<dim3(64,32), 256, 0, stream>>>(src, tgt, ws, ws + WS_LAT);
  kp_mlp_kernel<<<32, 128, 0, stream>>>(ws,
      (const float*)d_in[20], (const float*)d_in[21],
      (const float*)d_in[22], (const float*)d_in[23], ws);
  fps_kernel<<<32, 256, 0, stream>>>(src, tgt, ws, out);
  pminmax_kernel<<<16, 256, 0, stream>>>(src, ws);
  cage_mlp_kernel<<<16, 256, 0, stream>>>(ws,
      (const float*)d_in[24], (const float*)d_in[25],
      (const float*)d_in[26], (const float*)d_in[27], ws);
  deform_kernel<<<dim3(64,16), 256, 0, stream>>>(src, ws, out);
}